// Round 3
// baseline (681.608 us; speedup 1.0000x reference)
//
#include <hip/hip_runtime.h>
#include <cstdint>

typedef unsigned int u32;
typedef unsigned short u16;

#define NN 50000
#define NE 1600000

typedef __bf16 bf16x8 __attribute__((ext_vector_type(8)));
typedef float f32x4 __attribute__((ext_vector_type(4)));

// ---------------- threefry2x32-20 ----------------
__host__ __device__ static inline void tf2x32(u32 ka, u32 kb, u32 x0, u32 x1,
                                              u32& o0, u32& o1) {
  const u32 kc = ka ^ kb ^ 0x1BD11BDAu;
  u32 v0 = x0 + ka, v1 = x1 + kb;
#define TFR(r) { v0 += v1; v1 = (v1 << (r)) | (v1 >> (32 - (r))); v1 ^= v0; }
  TFR(13) TFR(15) TFR(26) TFR(6)   v0 += kb; v1 += kc + 1u;
  TFR(17) TFR(29) TFR(16) TFR(24)  v0 += kc; v1 += ka + 2u;
  TFR(13) TFR(15) TFR(26) TFR(6)   v0 += ka; v1 += kb + 3u;
  TFR(17) TFR(29) TFR(16) TFR(24)  v0 += kb; v1 += kc + 4u;
  TFR(13) TFR(15) TFR(26) TFR(6)   v0 += kc; v1 += ka + 5u;
#undef TFR
  o0 = v0; o1 = v1;
}

// partitionable threefry random_bits: element j -> xor of cipher(key, (0, j))
__device__ static inline u32 tfbits(u32 ka, u32 kb, u32 j) {
  u32 o0, o1;
  tf2x32(ka, kb, 0u, j, o0, o1);
  return o0 ^ o1;
}

__device__ static inline float u01(u32 bits) {
  return __uint_as_float((bits >> 9) | 0x3f800000u) - 1.0f;
}
__device__ static inline u16 f2bf(float f) {  // RNE
  u32 u = __float_as_uint(f);
  return (u16)((u + 0x7fffu + ((u >> 16) & 1u)) >> 16);
}
__device__ static inline float bfbits2f(u32 lo16) { return __uint_as_float(lo16 << 16); }

// ---------------- int64-vs-int32 edge dtype detection ----------------
__global__ void detect_kernel(const int* __restrict__ ei, int* __restrict__ flag) {
  if (threadIdx.x == 0) {
    int allz = 1;
    for (int i = 0; i < 128; i++) {
      if (ei[2 * i + 1] != 0) { allz = 0; break; }
    }
    *flag = allz;
  }
}

__device__ static inline int eidx(const int* __restrict__ ei, int f64, int which, int i) {
  return f64 ? ei[2 * ((size_t)which * NE + i)] : ei[(size_t)which * NE + i];
}

// ---------------- weight prep: fp32 [K][256] -> bf16 Wt[n][k] (N-major) ----------------
__global__ __launch_bounds__(256) void prep_w_kernel(
    const float* __restrict__ wr0, const float* __restrict__ wroot0,
    const float* __restrict__ wr1, const float* __restrict__ wroot1,
    u16* __restrict__ Wt0, u16* __restrict__ Wt1) {
  int i = blockIdx.x * 256 + threadIdx.x;
  if (i < 256 * 256) {                    // Wt0: [n=256][k=256], k<128 rel, k>=128 root
    int n = i >> 8, k = i & 255;
    float v = (k < 128) ? wr0[k * 256 + n] : wroot0[(k - 128) * 256 + n];
    Wt0[n * 256 + k] = f2bf(v);
  }
  int j = i - 256 * 256;
  if (j >= 0 && j < 256 * 512) {          // Wt1: [n=256][k=512], k<256 rel, k>=256 root
    int n = j >> 9, k = j & 511;
    float v = (k < 256) ? wr1[k * 256 + n] : wroot1[(k - 256) * 256 + n];
    Wt1[n * 512 + k] = f2bf(v);
  }
}

// ---------------- dropout0: x fp32 -> h0 bf16 into A0 right half ----------------
__global__ __launch_bounds__(256) void drop0_kernel(const float* __restrict__ x,
                                                    u16* __restrict__ A0,
                                                    u32 ka, u32 kb) {
  int j = blockIdx.x * 256 + threadIdx.x;  // [0, 6.4M)
  float v = (u01(tfbits(ka, kb, (u32)j)) < 0.4f) ? x[j] * 2.5f : 0.0f;
  int r = j >> 7, c = j & 127;
  A0[r * 256 + 128 + c] = f2bf(v);
}

// ---------------- CSR build (counting sort by dst) ----------------
__global__ __launch_bounds__(256) void hist_kernel(const int* __restrict__ ei,
                                                   const int* __restrict__ flag,
                                                   int* __restrict__ deg) {
  int f = *flag;
  int i = blockIdx.x * 256 + threadIdx.x;
  if (i < NE) atomicAdd(&deg[eidx(ei, f, 1, i)], 1);
}

__global__ __launch_bounds__(1024) void scan_kernel(const int* __restrict__ deg,
                                                    int* __restrict__ offs,
                                                    int* __restrict__ cursor) {
  __shared__ int part[1024];
  const int CHUNK = (NN + 1023) / 1024;   // 49
  int t = threadIdx.x;
  int base = t * CHUNK;
  int sum = 0;
  for (int k = 0; k < CHUNK; k++) { int i = base + k; if (i < NN) sum += deg[i]; }
  part[t] = sum;
  __syncthreads();
  for (int d = 1; d < 1024; d <<= 1) {
    int v = (t >= d) ? part[t - d] : 0;
    __syncthreads();
    part[t] += v;
    __syncthreads();
  }
  int run = (t == 0) ? 0 : part[t - 1];
  for (int k = 0; k < CHUNK; k++) {
    int i = base + k;
    if (i < NN) { offs[i] = run; cursor[i] = run; run += deg[i]; }
  }
  if (t == 1023) offs[NN] = part[1023];
}

__global__ __launch_bounds__(256) void scatter_kernel(const int* __restrict__ ei,
                                                      const int* __restrict__ flag,
                                                      int* __restrict__ cursor,
                                                      int* __restrict__ ssrc) {
  int f = *flag;
  int i = blockIdx.x * 256 + threadIdx.x;
  if (i < NE) {
    int p = atomicAdd(&cursor[eidx(ei, f, 1, i)], 1);
    ssrc[p] = eidx(ei, f, 0, i);
  }
}

// ---------------- aggregation: one wave per node ----------------
__global__ __launch_bounds__(256) void agg0_kernel(u16* __restrict__ A0,
                                                   const int* __restrict__ offs,
                                                   const int* __restrict__ ssrc) {
  int wid = (blockIdx.x << 2) | (threadIdx.x >> 6);
  if (wid >= NN) return;
  int lane = threadIdx.x & 63;
  int s = offs[wid], e = offs[wid + 1];
  float a0 = 0.f, a1 = 0.f;
  int i = s;
  for (; i + 4 <= e; i += 4) {
    int s0 = ssrc[i], s1 = ssrc[i + 1], s2 = ssrc[i + 2], s3 = ssrc[i + 3];
    u32 v0 = *(const u32*)&A0[s0 * 256 + 128 + lane * 2];
    u32 v1 = *(const u32*)&A0[s1 * 256 + 128 + lane * 2];
    u32 v2 = *(const u32*)&A0[s2 * 256 + 128 + lane * 2];
    u32 v3 = *(const u32*)&A0[s3 * 256 + 128 + lane * 2];
    a0 += bfbits2f(v0 & 0xffffu) + bfbits2f(v1 & 0xffffu) +
          bfbits2f(v2 & 0xffffu) + bfbits2f(v3 & 0xffffu);
    a1 += bfbits2f(v0 >> 16) + bfbits2f(v1 >> 16) +
          bfbits2f(v2 >> 16) + bfbits2f(v3 >> 16);
  }
  for (; i < e; i++) {
    u32 v = *(const u32*)&A0[ssrc[i] * 256 + 128 + lane * 2];
    a0 += bfbits2f(v & 0xffffu);
    a1 += bfbits2f(v >> 16);
  }
  u32 o = (u32)f2bf(a0) | ((u32)f2bf(a1) << 16);
  *(u32*)&A0[wid * 256 + lane * 2] = o;
}

__global__ __launch_bounds__(256) void agg1_kernel(u16* __restrict__ A1,
                                                   const int* __restrict__ offs,
                                                   const int* __restrict__ ssrc) {
  int wid = (blockIdx.x << 2) | (threadIdx.x >> 6);
  if (wid >= NN) return;
  int lane = threadIdx.x & 63;
  int s = offs[wid], e = offs[wid + 1];
  float a0 = 0.f, a1 = 0.f, a2 = 0.f, a3 = 0.f;
  int i = s;
  for (; i + 4 <= e; i += 4) {
    int s0 = ssrc[i], s1 = ssrc[i + 1], s2 = ssrc[i + 2], s3 = ssrc[i + 3];
    uint2 v0 = *(const uint2*)&A1[s0 * 512 + 256 + lane * 4];
    uint2 v1 = *(const uint2*)&A1[s1 * 512 + 256 + lane * 4];
    uint2 v2 = *(const uint2*)&A1[s2 * 512 + 256 + lane * 4];
    uint2 v3 = *(const uint2*)&A1[s3 * 512 + 256 + lane * 4];
    a0 += bfbits2f(v0.x & 0xffffu) + bfbits2f(v1.x & 0xffffu) +
          bfbits2f(v2.x & 0xffffu) + bfbits2f(v3.x & 0xffffu);
    a1 += bfbits2f(v0.x >> 16) + bfbits2f(v1.x >> 16) +
          bfbits2f(v2.x >> 16) + bfbits2f(v3.x >> 16);
    a2 += bfbits2f(v0.y & 0xffffu) + bfbits2f(v1.y & 0xffffu) +
          bfbits2f(v2.y & 0xffffu) + bfbits2f(v3.y & 0xffffu);
    a3 += bfbits2f(v0.y >> 16) + bfbits2f(v1.y >> 16) +
          bfbits2f(v2.y >> 16) + bfbits2f(v3.y >> 16);
  }
  for (; i < e; i++) {
    uint2 v = *(const uint2*)&A1[ssrc[i] * 512 + 256 + lane * 4];
    a0 += bfbits2f(v.x & 0xffffu);
    a1 += bfbits2f(v.x >> 16);
    a2 += bfbits2f(v.y & 0xffffu);
    a3 += bfbits2f(v.y >> 16);
  }
  u32 o0 = (u32)f2bf(a0) | ((u32)f2bf(a1) << 16);
  u32 o1 = (u32)f2bf(a2) | ((u32)f2bf(a3) << 16);
  *(uint2*)&A1[wid * 512 + lane * 4] = make_uint2(o0, o1);
}

// ---------------- GEMM: C[16 rows x 256 cols per block] = A @ Wt^T + b ----------------
template <int K, bool DROP>
__global__ __launch_bounds__(256) void gemm_kernel(const u16* __restrict__ A,
                                                   const u16* __restrict__ Wt,
                                                   const float* __restrict__ bias,
                                                   u16* __restrict__ outB,
                                                   float* __restrict__ outF,
                                                   u32 ka, u32 kb) {
  __shared__ __align__(16) u16 lds[16 * (K + 8)];
  const int tid = threadIdx.x;
  const int row0 = blockIdx.x * 16;

  constexpr int CHUNKS = 16 * K / 8;      // 16B chunks of the A strip
#pragma unroll
  for (int c = tid; c < CHUNKS; c += 256) {
    int r = c / (K / 8);
    int cc = c % (K / 8);
    *(uint4*)&lds[r * (K + 8) + cc * 8] = *(const uint4*)&A[(row0 + r) * K + cc * 8];
  }
  __syncthreads();

  const int lane = tid & 63;
  const int w = tid >> 6;
  const int lrow = lane & 15;
  const int lk = (lane >> 4) * 8;

  f32x4 acc[4] = {{0.f, 0.f, 0.f, 0.f}, {0.f, 0.f, 0.f, 0.f},
                  {0.f, 0.f, 0.f, 0.f}, {0.f, 0.f, 0.f, 0.f}};
#pragma unroll
  for (int ks = 0; ks < K / 32; ks++) {
    bf16x8 a = *(const bf16x8*)&lds[lrow * (K + 8) + ks * 32 + lk];
#pragma unroll
    for (int t = 0; t < 4; t++) {
      bf16x8 b = *(const bf16x8*)&Wt[(w * 64 + t * 16 + lrow) * K + ks * 32 + lk];
      acc[t] = __builtin_amdgcn_mfma_f32_16x16x32_bf16(a, b, acc[t], 0, 0, 0);
    }
  }

#pragma unroll
  for (int t = 0; t < 4; t++) {
    int col = w * 64 + t * 16 + lrow;
    float bv = bias[col];
#pragma unroll
    for (int r = 0; r < 4; r++) {
      int row = row0 + (lane >> 4) * 4 + r;
      float v = acc[t][r] + bv;
      v = fmaxf(v, 0.0f);
      if constexpr (DROP) {
        u32 j = (u32)row * 256u + (u32)col;     // flat index in [NN x 256]
        v = (u01(tfbits(ka, kb, j)) < 0.4f) ? v * 2.5f : 0.0f;
        outB[row * 512 + 256 + col] = f2bf(v);
      } else {
        outF[row * 256 + col] = v;
      }
    }
  }
}

// ---------------- host launch ----------------
extern "C" void kernel_launch(void* const* d_in, const int* in_sizes, int n_in,
                              void* d_out, int out_size, void* d_ws, size_t ws_size,
                              hipStream_t stream) {
  (void)in_sizes; (void)n_in; (void)out_size; (void)ws_size;
  const float* x       = (const float*)d_in[0];
  const int*   ei      = (const int*)d_in[1];
  const float* w_rel0  = (const float*)d_in[2];
  const float* b_rel0  = (const float*)d_in[3];
  const float* w_root0 = (const float*)d_in[4];
  const float* w_rel1  = (const float*)d_in[5];
  const float* b_rel1  = (const float*)d_in[6];
  const float* w_root1 = (const float*)d_in[7];
  float* out = (float*)d_out;

  // partitionable (foldlike) split of key(42): subkey i = cipher(key, (0, i))
  u32 k0a, k0b, k1a, k1b;
  tf2x32(0u, 42u, 0u, 0u, k0a, k0b);   // first subkey  (dropout on x)
  tf2x32(0u, 42u, 0u, 1u, k1a, k1b);   // second subkey (dropout on h)

  // workspace carve (256B aligned) — total ~33 MB
  uint8_t* p = (uint8_t*)d_ws;
  auto alloc = [&](size_t bytes) {
    uint8_t* r = p;
    p += (bytes + 255) & ~(size_t)255;
    return r;
  };
  u16* A0     = (u16*)alloc((size_t)NN * 256 * 2);   // [agg0 | h0]  25.6 MB
  u16* Wt0    = (u16*)alloc(256 * 256 * 2);
  u16* Wt1    = (u16*)alloc(256 * 512 * 2);
  int* deg    = (int*)alloc((size_t)NN * 4);
  int* offs   = (int*)alloc((size_t)(NN + 1) * 4);
  int* cursor = (int*)alloc((size_t)NN * 4);
  int* flag   = (int*)alloc(4);
  int* ssrc   = (int*)alloc((size_t)NE * 4);

  // A1 [50000][512] bf16 aliases d_out (50000*256 fp32 == 50000*512 u16 bytes)
  u16* A1 = (u16*)d_out;

  hipMemsetAsync(deg, 0, (size_t)NN * 4, stream);
  detect_kernel<<<1, 64, 0, stream>>>(ei, flag);
  prep_w_kernel<<<768, 256, 0, stream>>>(w_rel0, w_root0, w_rel1, w_root1, Wt0, Wt1);
  drop0_kernel<<<25000, 256, 0, stream>>>(x, A0, k0a, k0b);
  hist_kernel<<<6250, 256, 0, stream>>>(ei, flag, deg);
  scan_kernel<<<1, 1024, 0, stream>>>(deg, offs, cursor);
  scatter_kernel<<<6250, 256, 0, stream>>>(ei, flag, cursor, ssrc);
  agg0_kernel<<<12500, 256, 0, stream>>>(A0, offs, ssrc);
  gemm_kernel<256, true><<<3125, 256, 0, stream>>>(A0, Wt0, b_rel0, A1, nullptr, k1a, k1b);
  agg1_kernel<<<12500, 256, 0, stream>>>(A1, offs, ssrc);
  gemm_kernel<512, false><<<3125, 256, 0, stream>>>(A1, Wt1, b_rel1, nullptr, out, 0u, 0u);
}

// Round 4
// 632.736 us; speedup vs baseline: 1.0772x; 1.0772x over previous
//
#include <hip/hip_runtime.h>
#include <cstdint>

typedef unsigned int u32;
typedef unsigned short u16;

#define NN 50000
#define NE 1600000
#define NXCD 8
#define DST_PER_XCD 6250   // NN / NXCD

typedef __bf16 bf16x8 __attribute__((ext_vector_type(8)));
typedef float f32x4 __attribute__((ext_vector_type(4)));

// ---------------- threefry2x32-20 ----------------
__host__ __device__ static inline void tf2x32(u32 ka, u32 kb, u32 x0, u32 x1,
                                              u32& o0, u32& o1) {
  const u32 kc = ka ^ kb ^ 0x1BD11BDAu;
  u32 v0 = x0 + ka, v1 = x1 + kb;
#define TFR(r) { v0 += v1; v1 = (v1 << (r)) | (v1 >> (32 - (r))); v1 ^= v0; }
  TFR(13) TFR(15) TFR(26) TFR(6)   v0 += kb; v1 += kc + 1u;
  TFR(17) TFR(29) TFR(16) TFR(24)  v0 += kc; v1 += ka + 2u;
  TFR(13) TFR(15) TFR(26) TFR(6)   v0 += ka; v1 += kb + 3u;
  TFR(17) TFR(29) TFR(16) TFR(24)  v0 += kb; v1 += kc + 4u;
  TFR(13) TFR(15) TFR(26) TFR(6)   v0 += kc; v1 += ka + 5u;
#undef TFR
  o0 = v0; o1 = v1;
}

// partitionable threefry random_bits: element j -> xor of cipher(key, (0, j))
__device__ static inline u32 tfbits(u32 ka, u32 kb, u32 j) {
  u32 o0, o1;
  tf2x32(ka, kb, 0u, j, o0, o1);
  return o0 ^ o1;
}

__device__ static inline float u01(u32 bits) {
  return __uint_as_float((bits >> 9) | 0x3f800000u) - 1.0f;
}
__device__ static inline u16 f2bf(float f) {  // RNE
  u32 u = __float_as_uint(f);
  return (u16)((u + 0x7fffu + ((u >> 16) & 1u)) >> 16);
}
__device__ static inline float bfbits2f(u32 lo16) { return __uint_as_float(lo16 << 16); }

// ---------------- int64-vs-int32 edge dtype detection ----------------
__global__ void detect_kernel(const int* __restrict__ ei, int* __restrict__ flag) {
  if (threadIdx.x == 0) {
    int allz = 1;
    for (int i = 0; i < 128; i++) {
      if (ei[2 * i + 1] != 0) { allz = 0; break; }
    }
    *flag = allz;
  }
}

__device__ static inline int eidx(const int* __restrict__ ei, int f64, int which, int i) {
  return f64 ? ei[2 * ((size_t)which * NE + i)] : ei[(size_t)which * NE + i];
}

// ---------------- weight prep: fp32 [K][256] -> bf16 Wt[n][k] (N-major) ----------------
__global__ __launch_bounds__(256) void prep_w_kernel(
    const float* __restrict__ wr0, const float* __restrict__ wroot0,
    const float* __restrict__ wr1, const float* __restrict__ wroot1,
    u16* __restrict__ Wt0, u16* __restrict__ Wt1) {
  int i = blockIdx.x * 256 + threadIdx.x;
  if (i < 256 * 256) {                    // Wt0: [n=256][k=256], k<128 rel, k>=128 root
    int n = i >> 8, k = i & 255;
    float v = (k < 128) ? wr0[k * 256 + n] : wroot0[(k - 128) * 256 + n];
    Wt0[n * 256 + k] = f2bf(v);
  }
  int j = i - 256 * 256;
  if (j >= 0 && j < 256 * 512) {          // Wt1: [n=256][k=512], k<256 rel, k>=256 root
    int n = j >> 9, k = j & 511;
    float v = (k < 256) ? wr1[k * 256 + n] : wroot1[(k - 256) * 256 + n];
    Wt1[n * 512 + k] = f2bf(v);
  }
}

// ---------------- dropout0: x fp32 -> h0 bf16 into A0 right half ----------------
__global__ __launch_bounds__(256) void drop0_kernel(const float* __restrict__ x,
                                                    u16* __restrict__ A0,
                                                    u32 ka, u32 kb) {
  int j = blockIdx.x * 256 + threadIdx.x;  // [0, 6.4M)
  float v = (u01(tfbits(ka, kb, (u32)j)) < 0.4f) ? x[j] * 2.5f : 0.0f;
  int r = j >> 7, c = j & 127;
  A0[r * 256 + 128 + c] = f2bf(v);
}

// ---------------- CSR build (counting sort by dst) ----------------
__global__ __launch_bounds__(256) void hist_kernel(const int* __restrict__ ei,
                                                   const int* __restrict__ flag,
                                                   int* __restrict__ deg) {
  int f = *flag;
  int i = blockIdx.x * 256 + threadIdx.x;
  if (i < NE) atomicAdd(&deg[eidx(ei, f, 1, i)], 1);
}

__global__ __launch_bounds__(1024) void scan_kernel(const int* __restrict__ deg,
                                                    int* __restrict__ offs,
                                                    int* __restrict__ cursor) {
  __shared__ int part[1024];
  const int CHUNK = (NN + 1023) / 1024;   // 49
  int t = threadIdx.x;
  int base = t * CHUNK;
  int sum = 0;
  for (int k = 0; k < CHUNK; k++) { int i = base + k; if (i < NN) sum += deg[i]; }
  part[t] = sum;
  __syncthreads();
  for (int d = 1; d < 1024; d <<= 1) {
    int v = (t >= d) ? part[t - d] : 0;
    __syncthreads();
    part[t] += v;
    __syncthreads();
  }
  int run = (t == 0) ? 0 : part[t - 1];
  for (int k = 0; k < CHUNK; k++) {
    int i = base + k;
    if (i < NN) { offs[i] = run; cursor[i] = run; run += deg[i]; }
  }
  if (t == 1023) offs[NN] = part[1023];
}

// XCD-range-partitioned scatter: block b covers edge span (b>>3), but only
// commits edges whose dst is in range (b&7). bid%8 round-robins over XCDs,
// so each XCD's random ssrc writes stay inside a ~800KB slice that fits its
// private 4MB L2 -> lines fill fully in L2 and evict once (write ~6.4MB total
// instead of 1.6M x 64B line evictions).
#define SC_SPAN 2048                      // edges per block span
#define SC_NSPAN ((NE + SC_SPAN - 1) / SC_SPAN)   // 782

__global__ __launch_bounds__(256) void scatter_kernel(const int* __restrict__ ei,
                                                      const int* __restrict__ flag,
                                                      int* __restrict__ cursor,
                                                      int* __restrict__ ssrc) {
  int f = *flag;
  int xcd = blockIdx.x & (NXCD - 1);
  int span = blockIdx.x >> 3;
  int lo = xcd * DST_PER_XCD;
  int hi = lo + DST_PER_XCD;
  int base = span * SC_SPAN + threadIdx.x;
#pragma unroll
  for (int k = 0; k < SC_SPAN / 256; k++) {
    int i = base + k * 256;
    if (i < NE) {
      int d = eidx(ei, f, 1, i);
      if (d >= lo && d < hi) {
        int p = atomicAdd(&cursor[d], 1);
        ssrc[p] = eidx(ei, f, 0, i);
      }
    }
  }
}

// ---------------- aggregation: one wave per node ----------------
__global__ __launch_bounds__(256) void agg0_kernel(u16* __restrict__ A0,
                                                   const int* __restrict__ offs,
                                                   const int* __restrict__ ssrc) {
  int wid = (blockIdx.x << 2) | (threadIdx.x >> 6);
  if (wid >= NN) return;
  int lane = threadIdx.x & 63;
  int s = offs[wid], e = offs[wid + 1];
  float a0 = 0.f, a1 = 0.f;
  int i = s;
  for (; i + 4 <= e; i += 4) {
    int s0 = ssrc[i], s1 = ssrc[i + 1], s2 = ssrc[i + 2], s3 = ssrc[i + 3];
    u32 v0 = *(const u32*)&A0[s0 * 256 + 128 + lane * 2];
    u32 v1 = *(const u32*)&A0[s1 * 256 + 128 + lane * 2];
    u32 v2 = *(const u32*)&A0[s2 * 256 + 128 + lane * 2];
    u32 v3 = *(const u32*)&A0[s3 * 256 + 128 + lane * 2];
    a0 += bfbits2f(v0 & 0xffffu) + bfbits2f(v1 & 0xffffu) +
          bfbits2f(v2 & 0xffffu) + bfbits2f(v3 & 0xffffu);
    a1 += bfbits2f(v0 >> 16) + bfbits2f(v1 >> 16) +
          bfbits2f(v2 >> 16) + bfbits2f(v3 >> 16);
  }
  for (; i < e; i++) {
    u32 v = *(const u32*)&A0[ssrc[i] * 256 + 128 + lane * 2];
    a0 += bfbits2f(v & 0xffffu);
    a1 += bfbits2f(v >> 16);
  }
  u32 o = (u32)f2bf(a0) | ((u32)f2bf(a1) << 16);
  *(u32*)&A0[wid * 256 + lane * 2] = o;
}

__global__ __launch_bounds__(256) void agg1_kernel(u16* __restrict__ A1,
                                                   const int* __restrict__ offs,
                                                   const int* __restrict__ ssrc) {
  int wid = (blockIdx.x << 2) | (threadIdx.x >> 6);
  if (wid >= NN) return;
  int lane = threadIdx.x & 63;
  int s = offs[wid], e = offs[wid + 1];
  float a0 = 0.f, a1 = 0.f, a2 = 0.f, a3 = 0.f;
  int i = s;
  for (; i + 4 <= e; i += 4) {
    int s0 = ssrc[i], s1 = ssrc[i + 1], s2 = ssrc[i + 2], s3 = ssrc[i + 3];
    uint2 v0 = *(const uint2*)&A1[s0 * 512 + 256 + lane * 4];
    uint2 v1 = *(const uint2*)&A1[s1 * 512 + 256 + lane * 4];
    uint2 v2 = *(const uint2*)&A1[s2 * 512 + 256 + lane * 4];
    uint2 v3 = *(const uint2*)&A1[s3 * 512 + 256 + lane * 4];
    a0 += bfbits2f(v0.x & 0xffffu) + bfbits2f(v1.x & 0xffffu) +
          bfbits2f(v2.x & 0xffffu) + bfbits2f(v3.x & 0xffffu);
    a1 += bfbits2f(v0.x >> 16) + bfbits2f(v1.x >> 16) +
          bfbits2f(v2.x >> 16) + bfbits2f(v3.x >> 16);
    a2 += bfbits2f(v0.y & 0xffffu) + bfbits2f(v1.y & 0xffffu) +
          bfbits2f(v2.y & 0xffffu) + bfbits2f(v3.y & 0xffffu);
    a3 += bfbits2f(v0.y >> 16) + bfbits2f(v1.y >> 16) +
          bfbits2f(v2.y >> 16) + bfbits2f(v3.y >> 16);
  }
  for (; i < e; i++) {
    uint2 v = *(const uint2*)&A1[ssrc[i] * 512 + 256 + lane * 4];
    a0 += bfbits2f(v.x & 0xffffu);
    a1 += bfbits2f(v.x >> 16);
    a2 += bfbits2f(v.y & 0xffffu);
    a3 += bfbits2f(v.y >> 16);
  }
  u32 o0 = (u32)f2bf(a0) | ((u32)f2bf(a1) << 16);
  u32 o1 = (u32)f2bf(a2) | ((u32)f2bf(a3) << 16);
  *(uint2*)&A1[wid * 512 + lane * 4] = make_uint2(o0, o1);
}

// ---------------- GEMM: C[16 rows x 256 cols per block] = A @ Wt^T + b ----------------
template <int K, bool DROP>
__global__ __launch_bounds__(256) void gemm_kernel(const u16* __restrict__ A,
                                                   const u16* __restrict__ Wt,
                                                   const float* __restrict__ bias,
                                                   u16* __restrict__ outB,
                                                   float* __restrict__ outF,
                                                   u32 ka, u32 kb) {
  __shared__ __align__(16) u16 lds[16 * (K + 8)];
  const int tid = threadIdx.x;
  const int row0 = blockIdx.x * 16;

  constexpr int CHUNKS = 16 * K / 8;      // 16B chunks of the A strip
#pragma unroll
  for (int c = tid; c < CHUNKS; c += 256) {
    int r = c / (K / 8);
    int cc = c % (K / 8);
    *(uint4*)&lds[r * (K + 8) + cc * 8] = *(const uint4*)&A[(row0 + r) * K + cc * 8];
  }
  __syncthreads();

  const int lane = tid & 63;
  const int w = tid >> 6;
  const int lrow = lane & 15;
  const int lk = (lane >> 4) * 8;

  f32x4 acc[4] = {{0.f, 0.f, 0.f, 0.f}, {0.f, 0.f, 0.f, 0.f},
                  {0.f, 0.f, 0.f, 0.f}, {0.f, 0.f, 0.f, 0.f}};
#pragma unroll
  for (int ks = 0; ks < K / 32; ks++) {
    bf16x8 a = *(const bf16x8*)&lds[lrow * (K + 8) + ks * 32 + lk];
#pragma unroll
    for (int t = 0; t < 4; t++) {
      bf16x8 b = *(const bf16x8*)&Wt[(w * 64 + t * 16 + lrow) * K + ks * 32 + lk];
      acc[t] = __builtin_amdgcn_mfma_f32_16x16x32_bf16(a, b, acc[t], 0, 0, 0);
    }
  }

#pragma unroll
  for (int t = 0; t < 4; t++) {
    int col = w * 64 + t * 16 + lrow;
    float bv = bias[col];
#pragma unroll
    for (int r = 0; r < 4; r++) {
      int row = row0 + (lane >> 4) * 4 + r;
      float v = acc[t][r] + bv;
      v = fmaxf(v, 0.0f);
      if constexpr (DROP) {
        u32 j = (u32)row * 256u + (u32)col;     // flat index in [NN x 256]
        v = (u01(tfbits(ka, kb, j)) < 0.4f) ? v * 2.5f : 0.0f;
        outB[row * 512 + 256 + col] = f2bf(v);
      } else {
        outF[row * 256 + col] = v;
      }
    }
  }
}

// ---------------- host launch ----------------
extern "C" void kernel_launch(void* const* d_in, const int* in_sizes, int n_in,
                              void* d_out, int out_size, void* d_ws, size_t ws_size,
                              hipStream_t stream) {
  (void)in_sizes; (void)n_in; (void)out_size; (void)ws_size;
  const float* x       = (const float*)d_in[0];
  const int*   ei      = (const int*)d_in[1];
  const float* w_rel0  = (const float*)d_in[2];
  const float* b_rel0  = (const float*)d_in[3];
  const float* w_root0 = (const float*)d_in[4];
  const float* w_rel1  = (const float*)d_in[5];
  const float* b_rel1  = (const float*)d_in[6];
  const float* w_root1 = (const float*)d_in[7];
  float* out = (float*)d_out;

  // partitionable (foldlike) split of key(42): subkey i = cipher(key, (0, i))
  u32 k0a, k0b, k1a, k1b;
  tf2x32(0u, 42u, 0u, 0u, k0a, k0b);   // first subkey  (dropout on x)
  tf2x32(0u, 42u, 0u, 1u, k1a, k1b);   // second subkey (dropout on h)

  // workspace carve (256B aligned) — total ~33 MB
  uint8_t* p = (uint8_t*)d_ws;
  auto alloc = [&](size_t bytes) {
    uint8_t* r = p;
    p += (bytes + 255) & ~(size_t)255;
    return r;
  };
  u16* A0     = (u16*)alloc((size_t)NN * 256 * 2);   // [agg0 | h0]  25.6 MB
  u16* Wt0    = (u16*)alloc(256 * 256 * 2);
  u16* Wt1    = (u16*)alloc(256 * 512 * 2);
  int* deg    = (int*)alloc((size_t)NN * 4);
  int* offs   = (int*)alloc((size_t)(NN + 1) * 4);
  int* cursor = (int*)alloc((size_t)NN * 4);
  int* flag   = (int*)alloc(4);
  int* ssrc   = (int*)alloc((size_t)NE * 4);

  // A1 [50000][512] bf16 aliases d_out (50000*256 fp32 == 50000*512 u16 bytes)
  u16* A1 = (u16*)d_out;

  hipMemsetAsync(deg, 0, (size_t)NN * 4, stream);
  detect_kernel<<<1, 64, 0, stream>>>(ei, flag);
  prep_w_kernel<<<768, 256, 0, stream>>>(w_rel0, w_root0, w_rel1, w_root1, Wt0, Wt1);
  drop0_kernel<<<25000, 256, 0, stream>>>(x, A0, k0a, k0b);
  hist_kernel<<<6250, 256, 0, stream>>>(ei, flag, deg);
  scan_kernel<<<1, 1024, 0, stream>>>(deg, offs, cursor);
  scatter_kernel<<<SC_NSPAN * NXCD, 256, 0, stream>>>(ei, flag, cursor, ssrc);
  agg0_kernel<<<12500, 256, 0, stream>>>(A0, offs, ssrc);
  gemm_kernel<256, true><<<3125, 256, 0, stream>>>(A0, Wt0, b_rel0, A1, nullptr, k1a, k1b);
  agg1_kernel<<<12500, 256, 0, stream>>>(A1, offs, ssrc);
  gemm_kernel<512, false><<<3125, 256, 0, stream>>>(A1, Wt1, b_rel1, nullptr, out, 0u, 0u);
}

// Round 5
// 515.950 us; speedup vs baseline: 1.3211x; 1.2264x over previous
//
#include <hip/hip_runtime.h>
#include <cstdint>

typedef unsigned int u32;
typedef unsigned short u16;

#define NN 50000
#define NE 1600000
#define NXCD 8
#define DST_PER_XCD 6250   // NN / NXCD
#define SCAN_CHUNK 512
#define SCAN_NB ((NN + SCAN_CHUNK - 1) / SCAN_CHUNK)   // 98

typedef __bf16 bf16x8 __attribute__((ext_vector_type(8)));
typedef float f32x4 __attribute__((ext_vector_type(4)));

// ---------------- threefry2x32-20 ----------------
__host__ __device__ static inline void tf2x32(u32 ka, u32 kb, u32 x0, u32 x1,
                                              u32& o0, u32& o1) {
  const u32 kc = ka ^ kb ^ 0x1BD11BDAu;
  u32 v0 = x0 + ka, v1 = x1 + kb;
#define TFR(r) { v0 += v1; v1 = (v1 << (r)) | (v1 >> (32 - (r))); v1 ^= v0; }
  TFR(13) TFR(15) TFR(26) TFR(6)   v0 += kb; v1 += kc + 1u;
  TFR(17) TFR(29) TFR(16) TFR(24)  v0 += kc; v1 += ka + 2u;
  TFR(13) TFR(15) TFR(26) TFR(6)   v0 += ka; v1 += kb + 3u;
  TFR(17) TFR(29) TFR(16) TFR(24)  v0 += kb; v1 += kc + 4u;
  TFR(13) TFR(15) TFR(26) TFR(6)   v0 += kc; v1 += ka + 5u;
#undef TFR
  o0 = v0; o1 = v1;
}

// partitionable threefry random_bits: element j -> xor of cipher(key, (0, j))
__device__ static inline u32 tfbits(u32 ka, u32 kb, u32 j) {
  u32 o0, o1;
  tf2x32(ka, kb, 0u, j, o0, o1);
  return o0 ^ o1;
}

__device__ static inline float u01(u32 bits) {
  return __uint_as_float((bits >> 9) | 0x3f800000u) - 1.0f;
}
__device__ static inline u16 f2bf(float f) {  // RNE
  u32 u = __float_as_uint(f);
  return (u16)((u + 0x7fffu + ((u >> 16) & 1u)) >> 16);
}
__device__ static inline float bfbits2f(u32 lo16) { return __uint_as_float(lo16 << 16); }

// ---------------- int64-vs-int32 edge dtype detection (64 lanes + ballot) ----------------
__global__ void detect_kernel(const int* __restrict__ ei, int* __restrict__ flag) {
  int t = threadIdx.x;                      // 64 threads
  int nz = (ei[2 * t + 1] != 0) ? 1 : 0;
  unsigned long long b = __ballot(nz);
  if (t == 0) *flag = (b == 0ull) ? 1 : 0;
}

__device__ static inline int eidx(const int* __restrict__ ei, int f64, int which, int i) {
  return f64 ? ei[2 * ((size_t)which * NE + i)] : ei[(size_t)which * NE + i];
}

// ---------------- weight prep: fp32 [K][256] -> bf16 Wt[n][k] (N-major) ----------------
__global__ __launch_bounds__(256) void prep_w_kernel(
    const float* __restrict__ wr0, const float* __restrict__ wroot0,
    const float* __restrict__ wr1, const float* __restrict__ wroot1,
    u16* __restrict__ Wt0, u16* __restrict__ Wt1) {
  int i = blockIdx.x * 256 + threadIdx.x;
  if (i < 256 * 256) {                    // Wt0: [n=256][k=256], k<128 rel, k>=128 root
    int n = i >> 8, k = i & 255;
    float v = (k < 128) ? wr0[k * 256 + n] : wroot0[(k - 128) * 256 + n];
    Wt0[n * 256 + k] = f2bf(v);
  }
  int j = i - 256 * 256;
  if (j >= 0 && j < 256 * 512) {          // Wt1: [n=256][k=512], k<256 rel, k>=256 root
    int n = j >> 9, k = j & 511;
    float v = (k < 256) ? wr1[k * 256 + n] : wroot1[(k - 256) * 256 + n];
    Wt1[n * 512 + k] = f2bf(v);
  }
}

// ---------------- dropout0: x fp32 -> h0 bf16 into A0 right half ----------------
__global__ __launch_bounds__(256) void drop0_kernel(const float* __restrict__ x,
                                                    u16* __restrict__ A0,
                                                    u32 ka, u32 kb) {
  int j = blockIdx.x * 256 + threadIdx.x;  // [0, 6.4M)
  float v = (u01(tfbits(ka, kb, (u32)j)) < 0.4f) ? x[j] * 2.5f : 0.0f;
  int r = j >> 7, c = j & 127;
  A0[r * 256 + 128 + c] = f2bf(v);
}

// ---------------- CSR build (counting sort by dst) ----------------
__global__ __launch_bounds__(256) void hist_kernel(const int* __restrict__ ei,
                                                   const int* __restrict__ flag,
                                                   int* __restrict__ deg) {
  int f = *flag;
  int i = blockIdx.x * 256 + threadIdx.x;
  if (i < NE) atomicAdd(&deg[eidx(ei, f, 1, i)], 1);
}

// --- hierarchical scan: phase 1 — per-block chunk sums ---
__global__ __launch_bounds__(256) void scan_partial_kernel(const int* __restrict__ deg,
                                                           int* __restrict__ bsum) {
  __shared__ int red[256];
  int b = blockIdx.x, t = threadIdx.x;
  int i0 = b * SCAN_CHUNK + t * 2;
  int s = 0;
  if (i0 < NN) s += deg[i0];
  if (i0 + 1 < NN) s += deg[i0 + 1];
  red[t] = s;
  __syncthreads();
#pragma unroll
  for (int d = 128; d > 0; d >>= 1) {
    if (t < d) red[t] += red[t + d];
    __syncthreads();
  }
  if (t == 0) bsum[b] = red[0];
}

// --- phase 2 — exclusive scan of 98 block sums (1 block) ---
__global__ __launch_bounds__(128) void scan_bsums_kernel(int* __restrict__ bsum,
                                                         int* __restrict__ offs) {
  __shared__ int v[128];
  int t = threadIdx.x;
  int orig = (t < SCAN_NB) ? bsum[t] : 0;
  v[t] = orig;
  __syncthreads();
#pragma unroll
  for (int d = 1; d < 128; d <<= 1) {
    int x = (t >= d) ? v[t - d] : 0;
    __syncthreads();
    v[t] += x;
    __syncthreads();
  }
  if (t < SCAN_NB) bsum[t] = v[t] - orig;   // exclusive block offset
  if (t == 0) offs[NN] = v[SCAN_NB - 1];    // grand total (= NE)
}

// --- phase 3 — per-block local scan + write offs/cursor ---
__global__ __launch_bounds__(256) void scan_write_kernel(const int* __restrict__ deg,
                                                         const int* __restrict__ bsum,
                                                         int* __restrict__ offs,
                                                         int* __restrict__ cursor) {
  __shared__ int v[256];
  int b = blockIdx.x, t = threadIdx.x;
  int i0 = b * SCAN_CHUNK + t * 2;
  int d0 = (i0 < NN) ? deg[i0] : 0;
  int d1 = (i0 + 1 < NN) ? deg[i0 + 1] : 0;
  int tsum = d0 + d1;
  v[t] = tsum;
  __syncthreads();
#pragma unroll
  for (int d = 1; d < 256; d <<= 1) {
    int x = (t >= d) ? v[t - d] : 0;
    __syncthreads();
    v[t] += x;
    __syncthreads();
  }
  int excl = bsum[b] + v[t] - tsum;
  if (i0 < NN)     { offs[i0] = excl;          cursor[i0] = excl; }
  if (i0 + 1 < NN) { offs[i0 + 1] = excl + d0; cursor[i0 + 1] = excl + d0; }
}

// XCD-range-partitioned scatter (keeps each XCD's random writes in its L2 slice)
#define SC_SPAN 2048
#define SC_NSPAN ((NE + SC_SPAN - 1) / SC_SPAN)   // 782

__global__ __launch_bounds__(256) void scatter_kernel(const int* __restrict__ ei,
                                                      const int* __restrict__ flag,
                                                      int* __restrict__ cursor,
                                                      int* __restrict__ ssrc) {
  int f = *flag;
  int xcd = blockIdx.x & (NXCD - 1);
  int span = blockIdx.x >> 3;
  int lo = xcd * DST_PER_XCD;
  int hi = lo + DST_PER_XCD;
  int base = span * SC_SPAN + threadIdx.x;
#pragma unroll
  for (int k = 0; k < SC_SPAN / 256; k++) {
    int i = base + k * 256;
    if (i < NE) {
      int d = eidx(ei, f, 1, i);
      if (d >= lo && d < hi) {
        int p = atomicAdd(&cursor[d], 1);
        ssrc[p] = eidx(ei, f, 0, i);
      }
    }
  }
}

// ---------------- aggregation: one wave per node ----------------
__global__ __launch_bounds__(256) void agg0_kernel(u16* __restrict__ A0,
                                                   const int* __restrict__ offs,
                                                   const int* __restrict__ ssrc) {
  int wid = (blockIdx.x << 2) | (threadIdx.x >> 6);
  if (wid >= NN) return;
  int lane = threadIdx.x & 63;
  int s = offs[wid], e = offs[wid + 1];
  float a0 = 0.f, a1 = 0.f;
  int i = s;
  for (; i + 4 <= e; i += 4) {
    int s0 = ssrc[i], s1 = ssrc[i + 1], s2 = ssrc[i + 2], s3 = ssrc[i + 3];
    u32 v0 = *(const u32*)&A0[s0 * 256 + 128 + lane * 2];
    u32 v1 = *(const u32*)&A0[s1 * 256 + 128 + lane * 2];
    u32 v2 = *(const u32*)&A0[s2 * 256 + 128 + lane * 2];
    u32 v3 = *(const u32*)&A0[s3 * 256 + 128 + lane * 2];
    a0 += bfbits2f(v0 & 0xffffu) + bfbits2f(v1 & 0xffffu) +
          bfbits2f(v2 & 0xffffu) + bfbits2f(v3 & 0xffffu);
    a1 += bfbits2f(v0 >> 16) + bfbits2f(v1 >> 16) +
          bfbits2f(v2 >> 16) + bfbits2f(v3 >> 16);
  }
  for (; i < e; i++) {
    u32 v = *(const u32*)&A0[ssrc[i] * 256 + 128 + lane * 2];
    a0 += bfbits2f(v & 0xffffu);
    a1 += bfbits2f(v >> 16);
  }
  u32 o = (u32)f2bf(a0) | ((u32)f2bf(a1) << 16);
  *(u32*)&A0[wid * 256 + lane * 2] = o;
}

__global__ __launch_bounds__(256) void agg1_kernel(u16* __restrict__ A1,
                                                   const int* __restrict__ offs,
                                                   const int* __restrict__ ssrc) {
  int wid = (blockIdx.x << 2) | (threadIdx.x >> 6);
  if (wid >= NN) return;
  int lane = threadIdx.x & 63;
  int s = offs[wid], e = offs[wid + 1];
  float a0 = 0.f, a1 = 0.f, a2 = 0.f, a3 = 0.f;
  int i = s;
  for (; i + 4 <= e; i += 4) {
    int s0 = ssrc[i], s1 = ssrc[i + 1], s2 = ssrc[i + 2], s3 = ssrc[i + 3];
    uint2 v0 = *(const uint2*)&A1[s0 * 512 + 256 + lane * 4];
    uint2 v1 = *(const uint2*)&A1[s1 * 512 + 256 + lane * 4];
    uint2 v2 = *(const uint2*)&A1[s2 * 512 + 256 + lane * 4];
    uint2 v3 = *(const uint2*)&A1[s3 * 512 + 256 + lane * 4];
    a0 += bfbits2f(v0.x & 0xffffu) + bfbits2f(v1.x & 0xffffu) +
          bfbits2f(v2.x & 0xffffu) + bfbits2f(v3.x & 0xffffu);
    a1 += bfbits2f(v0.x >> 16) + bfbits2f(v1.x >> 16) +
          bfbits2f(v2.x >> 16) + bfbits2f(v3.x >> 16);
    a2 += bfbits2f(v0.y & 0xffffu) + bfbits2f(v1.y & 0xffffu) +
          bfbits2f(v2.y & 0xffffu) + bfbits2f(v3.y & 0xffffu);
    a3 += bfbits2f(v0.y >> 16) + bfbits2f(v1.y >> 16) +
          bfbits2f(v2.y >> 16) + bfbits2f(v3.y >> 16);
  }
  for (; i < e; i++) {
    uint2 v = *(const uint2*)&A1[ssrc[i] * 512 + 256 + lane * 4];
    a0 += bfbits2f(v.x & 0xffffu);
    a1 += bfbits2f(v.x >> 16);
    a2 += bfbits2f(v.y & 0xffffu);
    a3 += bfbits2f(v.y >> 16);
  }
  u32 o0 = (u32)f2bf(a0) | ((u32)f2bf(a1) << 16);
  u32 o1 = (u32)f2bf(a2) | ((u32)f2bf(a3) << 16);
  *(uint2*)&A1[wid * 512 + lane * 4] = make_uint2(o0, o1);
}

// ---------------- GEMM: C[16 rows x 256 cols per block] = A @ Wt^T + b ----------------
template <int K, bool DROP>
__global__ __launch_bounds__(256) void gemm_kernel(const u16* __restrict__ A,
                                                   const u16* __restrict__ Wt,
                                                   const float* __restrict__ bias,
                                                   u16* __restrict__ outB,
                                                   float* __restrict__ outF,
                                                   u32 ka, u32 kb) {
  __shared__ __align__(16) u16 lds[16 * (K + 8)];
  const int tid = threadIdx.x;
  const int row0 = blockIdx.x * 16;

  constexpr int CHUNKS = 16 * K / 8;      // 16B chunks of the A strip
#pragma unroll
  for (int c = tid; c < CHUNKS; c += 256) {
    int r = c / (K / 8);
    int cc = c % (K / 8);
    *(uint4*)&lds[r * (K + 8) + cc * 8] = *(const uint4*)&A[(row0 + r) * K + cc * 8];
  }
  __syncthreads();

  const int lane = tid & 63;
  const int w = tid >> 6;
  const int lrow = lane & 15;
  const int lk = (lane >> 4) * 8;

  f32x4 acc[4] = {{0.f, 0.f, 0.f, 0.f}, {0.f, 0.f, 0.f, 0.f},
                  {0.f, 0.f, 0.f, 0.f}, {0.f, 0.f, 0.f, 0.f}};
#pragma unroll
  for (int ks = 0; ks < K / 32; ks++) {
    bf16x8 a = *(const bf16x8*)&lds[lrow * (K + 8) + ks * 32 + lk];
#pragma unroll
    for (int t = 0; t < 4; t++) {
      bf16x8 b = *(const bf16x8*)&Wt[(w * 64 + t * 16 + lrow) * K + ks * 32 + lk];
      acc[t] = __builtin_amdgcn_mfma_f32_16x16x32_bf16(a, b, acc[t], 0, 0, 0);
    }
  }

#pragma unroll
  for (int t = 0; t < 4; t++) {
    int col = w * 64 + t * 16 + lrow;
    float bv = bias[col];
#pragma unroll
    for (int r = 0; r < 4; r++) {
      int row = row0 + (lane >> 4) * 4 + r;
      float v = acc[t][r] + bv;
      v = fmaxf(v, 0.0f);
      if constexpr (DROP) {
        u32 j = (u32)row * 256u + (u32)col;     // flat index in [NN x 256]
        v = (u01(tfbits(ka, kb, j)) < 0.4f) ? v * 2.5f : 0.0f;
        outB[row * 512 + 256 + col] = f2bf(v);
      } else {
        outF[row * 256 + col] = v;
      }
    }
  }
}

// ---------------- host launch ----------------
extern "C" void kernel_launch(void* const* d_in, const int* in_sizes, int n_in,
                              void* d_out, int out_size, void* d_ws, size_t ws_size,
                              hipStream_t stream) {
  (void)in_sizes; (void)n_in; (void)out_size; (void)ws_size;
  const float* x       = (const float*)d_in[0];
  const int*   ei      = (const int*)d_in[1];
  const float* w_rel0  = (const float*)d_in[2];
  const float* b_rel0  = (const float*)d_in[3];
  const float* w_root0 = (const float*)d_in[4];
  const float* w_rel1  = (const float*)d_in[5];
  const float* b_rel1  = (const float*)d_in[6];
  const float* w_root1 = (const float*)d_in[7];
  float* out = (float*)d_out;

  // partitionable (foldlike) split of key(42): subkey i = cipher(key, (0, i))
  u32 k0a, k0b, k1a, k1b;
  tf2x32(0u, 42u, 0u, 0u, k0a, k0b);   // first subkey  (dropout on x)
  tf2x32(0u, 42u, 0u, 1u, k1a, k1b);   // second subkey (dropout on h)

  // workspace carve (256B aligned) — total ~33 MB
  uint8_t* p = (uint8_t*)d_ws;
  auto alloc = [&](size_t bytes) {
    uint8_t* r = p;
    p += (bytes + 255) & ~(size_t)255;
    return r;
  };
  u16* A0     = (u16*)alloc((size_t)NN * 256 * 2);   // [agg0 | h0]  25.6 MB
  u16* Wt0    = (u16*)alloc(256 * 256 * 2);
  u16* Wt1    = (u16*)alloc(256 * 512 * 2);
  int* deg    = (int*)alloc((size_t)NN * 4);
  int* offs   = (int*)alloc((size_t)(NN + 1) * 4);
  int* cursor = (int*)alloc((size_t)NN * 4);
  int* bsum   = (int*)alloc((size_t)SCAN_NB * 4);
  int* flag   = (int*)alloc(4);
  int* ssrc   = (int*)alloc((size_t)NE * 4);

  // A1 [50000][512] bf16 aliases d_out (50000*256 fp32 == 50000*512 u16 bytes)
  u16* A1 = (u16*)d_out;

  hipMemsetAsync(deg, 0, (size_t)NN * 4, stream);
  detect_kernel<<<1, 64, 0, stream>>>(ei, flag);
  prep_w_kernel<<<768, 256, 0, stream>>>(w_rel0, w_root0, w_rel1, w_root1, Wt0, Wt1);
  drop0_kernel<<<25000, 256, 0, stream>>>(x, A0, k0a, k0b);
  hist_kernel<<<6250, 256, 0, stream>>>(ei, flag, deg);
  scan_partial_kernel<<<SCAN_NB, 256, 0, stream>>>(deg, bsum);
  scan_bsums_kernel<<<1, 128, 0, stream>>>(bsum, offs);
  scan_write_kernel<<<SCAN_NB, 256, 0, stream>>>(deg, bsum, offs, cursor);
  scatter_kernel<<<SC_NSPAN * NXCD, 256, 0, stream>>>(ei, flag, cursor, ssrc);
  agg0_kernel<<<12500, 256, 0, stream>>>(A0, offs, ssrc);
  gemm_kernel<256, true><<<3125, 256, 0, stream>>>(A0, Wt0, b_rel0, A1, nullptr, k1a, k1b);
  agg1_kernel<<<12500, 256, 0, stream>>>(A1, offs, ssrc);
  gemm_kernel<512, false><<<3125, 256, 0, stream>>>(A1, Wt1, b_rel1, nullptr, out, 0u, 0u);
}

// Round 6
// 432.842 us; speedup vs baseline: 1.5747x; 1.1920x over previous
//
#include <hip/hip_runtime.h>
#include <cstdint>

typedef unsigned int u32;
typedef unsigned short u16;

#define NN 50000
#define NE 1600000
#define NXCD 8
#define DST_PER_XCD 6250   // NN / NXCD
#define SCAN_CHUNK 512
#define SCAN_NB ((NN + SCAN_CHUNK - 1) / SCAN_CHUNK)   // 98

typedef __bf16 bf16x8 __attribute__((ext_vector_type(8)));
typedef float f32x4 __attribute__((ext_vector_type(4)));
typedef float f32x16 __attribute__((ext_vector_type(16)));

// ---------------- threefry2x32-20 ----------------
__host__ __device__ static inline void tf2x32(u32 ka, u32 kb, u32 x0, u32 x1,
                                              u32& o0, u32& o1) {
  const u32 kc = ka ^ kb ^ 0x1BD11BDAu;
  u32 v0 = x0 + ka, v1 = x1 + kb;
#define TFR(r) { v0 += v1; v1 = (v1 << (r)) | (v1 >> (32 - (r))); v1 ^= v0; }
  TFR(13) TFR(15) TFR(26) TFR(6)   v0 += kb; v1 += kc + 1u;
  TFR(17) TFR(29) TFR(16) TFR(24)  v0 += kc; v1 += ka + 2u;
  TFR(13) TFR(15) TFR(26) TFR(6)   v0 += ka; v1 += kb + 3u;
  TFR(17) TFR(29) TFR(16) TFR(24)  v0 += kb; v1 += kc + 4u;
  TFR(13) TFR(15) TFR(26) TFR(6)   v0 += kc; v1 += ka + 5u;
#undef TFR
  o0 = v0; o1 = v1;
}

// partitionable threefry random_bits: element j -> xor of cipher(key, (0, j))
__device__ static inline u32 tfbits(u32 ka, u32 kb, u32 j) {
  u32 o0, o1;
  tf2x32(ka, kb, 0u, j, o0, o1);
  return o0 ^ o1;
}

__device__ static inline float u01(u32 bits) {
  return __uint_as_float((bits >> 9) | 0x3f800000u) - 1.0f;
}
__device__ static inline u16 f2bf(float f) {  // RNE
  u32 u = __float_as_uint(f);
  return (u16)((u + 0x7fffu + ((u >> 16) & 1u)) >> 16);
}
__device__ static inline float bfbits2f(u32 lo16) { return __uint_as_float(lo16 << 16); }

// ---------------- int64-vs-int32 edge dtype detection (64 lanes + ballot) ----------------
__global__ void detect_kernel(const int* __restrict__ ei, int* __restrict__ flag) {
  int t = threadIdx.x;                      // 64 threads
  int nz = (ei[2 * t + 1] != 0) ? 1 : 0;
  unsigned long long b = __ballot(nz);
  if (t == 0) *flag = (b == 0ull) ? 1 : 0;
}

__device__ static inline int eidx(const int* __restrict__ ei, int f64, int which, int i) {
  return f64 ? ei[2 * ((size_t)which * NE + i)] : ei[(size_t)which * NE + i];
}

// ---------------- weight prep: fp32 [K][256] -> bf16 Wt[n][k] (N-major) ----------------
__global__ __launch_bounds__(256) void prep_w_kernel(
    const float* __restrict__ wr0, const float* __restrict__ wroot0,
    const float* __restrict__ wr1, const float* __restrict__ wroot1,
    u16* __restrict__ Wt0, u16* __restrict__ Wt1) {
  int i = blockIdx.x * 256 + threadIdx.x;
  if (i < 256 * 256) {                    // Wt0: [n=256][k=256], k<128 rel, k>=128 root
    int n = i >> 8, k = i & 255;
    float v = (k < 128) ? wr0[k * 256 + n] : wroot0[(k - 128) * 256 + n];
    Wt0[n * 256 + k] = f2bf(v);
  }
  int j = i - 256 * 256;
  if (j >= 0 && j < 256 * 512) {          // Wt1: [n=256][k=512], k<256 rel, k>=256 root
    int n = j >> 9, k = j & 511;
    float v = (k < 256) ? wr1[k * 256 + n] : wroot1[(k - 256) * 256 + n];
    Wt1[n * 512 + k] = f2bf(v);
  }
}

// ---------------- dropout0: x fp32 -> h0 bf16 into A0 right half ----------------
__global__ __launch_bounds__(256) void drop0_kernel(const float* __restrict__ x,
                                                    u16* __restrict__ A0,
                                                    u32 ka, u32 kb) {
  int j = blockIdx.x * 256 + threadIdx.x;  // [0, 6.4M)
  float v = (u01(tfbits(ka, kb, (u32)j)) < 0.4f) ? x[j] * 2.5f : 0.0f;
  int r = j >> 7, c = j & 127;
  A0[r * 256 + 128 + c] = f2bf(v);
}

// ---------------- CSR build (counting sort by dst) ----------------
__global__ __launch_bounds__(256) void hist_kernel(const int* __restrict__ ei,
                                                   const int* __restrict__ flag,
                                                   int* __restrict__ deg) {
  int f = *flag;
  int i = blockIdx.x * 256 + threadIdx.x;
  if (i < NE) atomicAdd(&deg[eidx(ei, f, 1, i)], 1);
}

// --- hierarchical scan: phase 1 — per-block chunk sums ---
__global__ __launch_bounds__(256) void scan_partial_kernel(const int* __restrict__ deg,
                                                           int* __restrict__ bsum) {
  __shared__ int red[256];
  int b = blockIdx.x, t = threadIdx.x;
  int i0 = b * SCAN_CHUNK + t * 2;
  int s = 0;
  if (i0 < NN) s += deg[i0];
  if (i0 + 1 < NN) s += deg[i0 + 1];
  red[t] = s;
  __syncthreads();
#pragma unroll
  for (int d = 128; d > 0; d >>= 1) {
    if (t < d) red[t] += red[t + d];
    __syncthreads();
  }
  if (t == 0) bsum[b] = red[0];
}

// --- phase 2 — exclusive scan of 98 block sums (1 block) ---
__global__ __launch_bounds__(128) void scan_bsums_kernel(int* __restrict__ bsum,
                                                         int* __restrict__ offs) {
  __shared__ int v[128];
  int t = threadIdx.x;
  int orig = (t < SCAN_NB) ? bsum[t] : 0;
  v[t] = orig;
  __syncthreads();
#pragma unroll
  for (int d = 1; d < 128; d <<= 1) {
    int x = (t >= d) ? v[t - d] : 0;
    __syncthreads();
    v[t] += x;
    __syncthreads();
  }
  if (t < SCAN_NB) bsum[t] = v[t] - orig;   // exclusive block offset
  if (t == 0) offs[NN] = v[SCAN_NB - 1];    // grand total (= NE)
}

// --- phase 3 — per-block local scan + write offs/cursor ---
__global__ __launch_bounds__(256) void scan_write_kernel(const int* __restrict__ deg,
                                                         const int* __restrict__ bsum,
                                                         int* __restrict__ offs,
                                                         int* __restrict__ cursor) {
  __shared__ int v[256];
  int b = blockIdx.x, t = threadIdx.x;
  int i0 = b * SCAN_CHUNK + t * 2;
  int d0 = (i0 < NN) ? deg[i0] : 0;
  int d1 = (i0 + 1 < NN) ? deg[i0 + 1] : 0;
  int tsum = d0 + d1;
  v[t] = tsum;
  __syncthreads();
#pragma unroll
  for (int d = 1; d < 256; d <<= 1) {
    int x = (t >= d) ? v[t - d] : 0;
    __syncthreads();
    v[t] += x;
    __syncthreads();
  }
  int excl = bsum[b] + v[t] - tsum;
  if (i0 < NN)     { offs[i0] = excl;          cursor[i0] = excl; }
  if (i0 + 1 < NN) { offs[i0 + 1] = excl + d0; cursor[i0 + 1] = excl + d0; }
}

// XCD-range-partitioned scatter (keeps each XCD's random writes in its L2 slice)
#define SC_SPAN 2048
#define SC_NSPAN ((NE + SC_SPAN - 1) / SC_SPAN)   // 782

__global__ __launch_bounds__(256) void scatter_kernel(const int* __restrict__ ei,
                                                      const int* __restrict__ flag,
                                                      int* __restrict__ cursor,
                                                      int* __restrict__ ssrc) {
  int f = *flag;
  int xcd = blockIdx.x & (NXCD - 1);
  int span = blockIdx.x >> 3;
  int lo = xcd * DST_PER_XCD;
  int hi = lo + DST_PER_XCD;
  int base = span * SC_SPAN + threadIdx.x;
#pragma unroll
  for (int k = 0; k < SC_SPAN / 256; k++) {
    int i = base + k * 256;
    if (i < NE) {
      int d = eidx(ei, f, 1, i);
      if (d >= lo && d < hi) {
        int p = atomicAdd(&cursor[d], 1);
        ssrc[p] = eidx(ei, f, 0, i);
      }
    }
  }
}

// ---------------- aggregation: one wave per node ----------------
__global__ __launch_bounds__(256) void agg0_kernel(u16* __restrict__ A0,
                                                   const int* __restrict__ offs,
                                                   const int* __restrict__ ssrc) {
  int wid = (blockIdx.x << 2) | (threadIdx.x >> 6);
  if (wid >= NN) return;
  int lane = threadIdx.x & 63;
  int s = offs[wid], e = offs[wid + 1];
  float a0 = 0.f, a1 = 0.f;
  int i = s;
  for (; i + 4 <= e; i += 4) {
    int s0 = ssrc[i], s1 = ssrc[i + 1], s2 = ssrc[i + 2], s3 = ssrc[i + 3];
    u32 v0 = *(const u32*)&A0[s0 * 256 + 128 + lane * 2];
    u32 v1 = *(const u32*)&A0[s1 * 256 + 128 + lane * 2];
    u32 v2 = *(const u32*)&A0[s2 * 256 + 128 + lane * 2];
    u32 v3 = *(const u32*)&A0[s3 * 256 + 128 + lane * 2];
    a0 += bfbits2f(v0 & 0xffffu) + bfbits2f(v1 & 0xffffu) +
          bfbits2f(v2 & 0xffffu) + bfbits2f(v3 & 0xffffu);
    a1 += bfbits2f(v0 >> 16) + bfbits2f(v1 >> 16) +
          bfbits2f(v2 >> 16) + bfbits2f(v3 >> 16);
  }
  for (; i < e; i++) {
    u32 v = *(const u32*)&A0[ssrc[i] * 256 + 128 + lane * 2];
    a0 += bfbits2f(v & 0xffffu);
    a1 += bfbits2f(v >> 16);
  }
  u32 o = (u32)f2bf(a0) | ((u32)f2bf(a1) << 16);
  *(u32*)&A0[wid * 256 + lane * 2] = o;
}

__global__ __launch_bounds__(256) void agg1_kernel(u16* __restrict__ A1,
                                                   const int* __restrict__ offs,
                                                   const int* __restrict__ ssrc) {
  int wid = (blockIdx.x << 2) | (threadIdx.x >> 6);
  if (wid >= NN) return;
  int lane = threadIdx.x & 63;
  int s = offs[wid], e = offs[wid + 1];
  float a0 = 0.f, a1 = 0.f, a2 = 0.f, a3 = 0.f;
  int i = s;
  for (; i + 4 <= e; i += 4) {
    int s0 = ssrc[i], s1 = ssrc[i + 1], s2 = ssrc[i + 2], s3 = ssrc[i + 3];
    uint2 v0 = *(const uint2*)&A1[s0 * 512 + 256 + lane * 4];
    uint2 v1 = *(const uint2*)&A1[s1 * 512 + 256 + lane * 4];
    uint2 v2 = *(const uint2*)&A1[s2 * 512 + 256 + lane * 4];
    uint2 v3 = *(const uint2*)&A1[s3 * 512 + 256 + lane * 4];
    a0 += bfbits2f(v0.x & 0xffffu) + bfbits2f(v1.x & 0xffffu) +
          bfbits2f(v2.x & 0xffffu) + bfbits2f(v3.x & 0xffffu);
    a1 += bfbits2f(v0.x >> 16) + bfbits2f(v1.x >> 16) +
          bfbits2f(v2.x >> 16) + bfbits2f(v3.x >> 16);
    a2 += bfbits2f(v0.y & 0xffffu) + bfbits2f(v1.y & 0xffffu) +
          bfbits2f(v2.y & 0xffffu) + bfbits2f(v3.y & 0xffffu);
    a3 += bfbits2f(v0.y >> 16) + bfbits2f(v1.y >> 16) +
          bfbits2f(v2.y >> 16) + bfbits2f(v3.y >> 16);
  }
  for (; i < e; i++) {
    uint2 v = *(const uint2*)&A1[ssrc[i] * 512 + 256 + lane * 4];
    a0 += bfbits2f(v.x & 0xffffu);
    a1 += bfbits2f(v.x >> 16);
    a2 += bfbits2f(v.y & 0xffffu);
    a3 += bfbits2f(v.y >> 16);
  }
  u32 o0 = (u32)f2bf(a0) | ((u32)f2bf(a1) << 16);
  u32 o1 = (u32)f2bf(a2) | ((u32)f2bf(a3) << 16);
  *(uint2*)&A1[wid * 512 + lane * 4] = make_uint2(o0, o1);
}

// ---------------- GEMM: C[64 rows x 256 cols per block] = A @ Wt^T + b ----------------
// A: [NN][K] bf16, Wt: [256][K] bf16 (N-major). 4 waves; wave (wr,wc) owns
// rows wr*32..+32, cols wc*128..+128 (4 col-tiles of 32). 32x32x16 MFMA.
// B staged through LDS per BK=64 chunk (amortized over 64 rows).
// DROP=true: relu -> dropout(k1) -> bf16 into outB right half (stride 512, +256)
// DROP=false: relu -> fp32 into outF (stride 256). A and outF may alias: block
// reads only its own rows (all staging) before its epilogue writes them.
template <int K, bool DROP>
__global__ __launch_bounds__(256) void gemm_kernel(const u16* __restrict__ A,
                                                   const u16* __restrict__ Wt,
                                                   const float* __restrict__ bias,
                                                   u16* __restrict__ outB,
                                                   float* __restrict__ outF,
                                                   u32 ka, u32 kb) {
  constexpr int BK = 64;
  constexpr int LDP = BK + 8;             // 72 u16 per LDS row
  __shared__ __align__(16) u16 Alds[64 * LDP];    //  9.2 KB
  __shared__ __align__(16) u16 Blds[256 * LDP];   // 36.9 KB
  const int tid = threadIdx.x;
  const int row0 = blockIdx.x * 64;
  const int lane = tid & 63;
  const int wid = tid >> 6;
  const int wr = wid & 1;                 // row half: 0,1
  const int wc = wid >> 1;                // col half: 0,1
  const int l31 = lane & 31;
  const int lkhi = (lane >> 5) * 8;

  f32x16 acc[4];
#pragma unroll
  for (int i = 0; i < 4; i++)
#pragma unroll
    for (int j = 0; j < 16; j++) acc[i][j] = 0.0f;

#pragma unroll
  for (int kc = 0; kc < K / BK; kc++) {
    // stage A: 64 rows x 8 x 16B chunks, 2 per thread
#pragma unroll
    for (int i = 0; i < 2; i++) {
      int id = tid + i * 256;
      int r = id >> 3, c = id & 7;
      int rg = row0 + r; if (rg > NN - 1) rg = NN - 1;
      *(uint4*)&Alds[r * LDP + c * 8] =
          *(const uint4*)&A[(size_t)rg * K + kc * BK + c * 8];
    }
    // stage B: 256 rows x 8 x 16B chunks, 8 per thread
#pragma unroll
    for (int i = 0; i < 8; i++) {
      int id = tid + i * 256;
      int r = id >> 3, c = id & 7;
      *(uint4*)&Blds[r * LDP + c * 8] =
          *(const uint4*)&Wt[(size_t)r * K + kc * BK + c * 8];
    }
    __syncthreads();
#pragma unroll
    for (int ks = 0; ks < BK / 16; ks++) {
      bf16x8 a = *(const bf16x8*)&Alds[(wr * 32 + l31) * LDP + ks * 16 + lkhi];
#pragma unroll
      for (int ct = 0; ct < 4; ct++) {
        bf16x8 b = *(const bf16x8*)&Blds[(wc * 128 + ct * 32 + l31) * LDP + ks * 16 + lkhi];
        acc[ct] = __builtin_amdgcn_mfma_f32_32x32x16_bf16(a, b, acc[ct], 0, 0, 0);
      }
    }
    __syncthreads();
  }

  // epilogue: C/D layout (m74/m101): col = lane&31, row = (r&3)+8*(r>>2)+4*(lane>>5)
#pragma unroll
  for (int ct = 0; ct < 4; ct++) {
    int col = wc * 128 + ct * 32 + l31;
    float bv = bias[col];
#pragma unroll
    for (int r = 0; r < 16; r++) {
      int row = row0 + wr * 32 + (r & 3) + 8 * (r >> 2) + 4 * (lane >> 5);
      if (row < NN) {
        float v = acc[ct][r] + bv;
        v = fmaxf(v, 0.0f);
        if constexpr (DROP) {
          u32 j = (u32)row * 256u + (u32)col;
          v = (u01(tfbits(ka, kb, j)) < 0.4f) ? v * 2.5f : 0.0f;
          outB[(size_t)row * 512 + 256 + col] = f2bf(v);
        } else {
          outF[(size_t)row * 256 + col] = v;
        }
      }
    }
  }
}

// ---------------- host launch ----------------
extern "C" void kernel_launch(void* const* d_in, const int* in_sizes, int n_in,
                              void* d_out, int out_size, void* d_ws, size_t ws_size,
                              hipStream_t stream) {
  (void)in_sizes; (void)n_in; (void)out_size; (void)ws_size;
  const float* x       = (const float*)d_in[0];
  const int*   ei      = (const int*)d_in[1];
  const float* w_rel0  = (const float*)d_in[2];
  const float* b_rel0  = (const float*)d_in[3];
  const float* w_root0 = (const float*)d_in[4];
  const float* w_rel1  = (const float*)d_in[5];
  const float* b_rel1  = (const float*)d_in[6];
  const float* w_root1 = (const float*)d_in[7];
  float* out = (float*)d_out;

  // partitionable (foldlike) split of key(42): subkey i = cipher(key, (0, i))
  u32 k0a, k0b, k1a, k1b;
  tf2x32(0u, 42u, 0u, 0u, k0a, k0b);   // first subkey  (dropout on x)
  tf2x32(0u, 42u, 0u, 1u, k1a, k1b);   // second subkey (dropout on h)

  // workspace carve (256B aligned) — total ~33 MB
  uint8_t* p = (uint8_t*)d_ws;
  auto alloc = [&](size_t bytes) {
    uint8_t* r = p;
    p += (bytes + 255) & ~(size_t)255;
    return r;
  };
  u16* A0     = (u16*)alloc((size_t)NN * 256 * 2);   // [agg0 | h0]  25.6 MB
  u16* Wt0    = (u16*)alloc(256 * 256 * 2);
  u16* Wt1    = (u16*)alloc(256 * 512 * 2);
  int* deg    = (int*)alloc((size_t)NN * 4);
  int* offs   = (int*)alloc((size_t)(NN + 1) * 4);
  int* cursor = (int*)alloc((size_t)NN * 4);
  int* bsum   = (int*)alloc((size_t)SCAN_NB * 4);
  int* flag   = (int*)alloc(4);
  int* ssrc   = (int*)alloc((size_t)NE * 4);

  // A1 [50000][512] bf16 aliases d_out (50000*256 fp32 == 50000*512 u16 bytes)
  u16* A1 = (u16*)d_out;

  const int GEMM_NB = (NN + 63) / 64;   // 782

  hipMemsetAsync(deg, 0, (size_t)NN * 4, stream);
  detect_kernel<<<1, 64, 0, stream>>>(ei, flag);
  prep_w_kernel<<<768, 256, 0, stream>>>(w_rel0, w_root0, w_rel1, w_root1, Wt0, Wt1);
  drop0_kernel<<<25000, 256, 0, stream>>>(x, A0, k0a, k0b);
  hist_kernel<<<6250, 256, 0, stream>>>(ei, flag, deg);
  scan_partial_kernel<<<SCAN_NB, 256, 0, stream>>>(deg, bsum);
  scan_bsums_kernel<<<1, 128, 0, stream>>>(bsum, offs);
  scan_write_kernel<<<SCAN_NB, 256, 0, stream>>>(deg, bsum, offs, cursor);
  scatter_kernel<<<SC_NSPAN * NXCD, 256, 0, stream>>>(ei, flag, cursor, ssrc);
  agg0_kernel<<<12500, 256, 0, stream>>>(A0, offs, ssrc);
  gemm_kernel<256, true><<<GEMM_NB, 256, 0, stream>>>(A0, Wt0, b_rel0, A1, nullptr, k1a, k1b);
  agg1_kernel<<<12500, 256, 0, stream>>>(A1, offs, ssrc);
  gemm_kernel<512, false><<<GEMM_NB, 256, 0, stream>>>(A1, Wt1, b_rel1, nullptr, out, 0u, 0u);
}